// Round 3
// baseline (626.325 us; speedup 1.0000x reference)
//
#include <hip/hip_runtime.h>

// ---------------------------------------------------------------------------
// STN pipeline. Conv chain + fc in FP64 (exact match to the harness's float64
// np reference is required: theta feeds a sampler with discontinuities at
// coord==223 whose jump magnitude is ~w_extrapolated*|I| ~ O(100-1000);
// fp32 conv noise (~3e-6) perturbs xf by ~6e-5 px and flips floor() at a few
// of the ~28k discontinuity-line crossings -> absmax ~100 > 79 threshold.
// FP64 everywhere upstream of the floor() kills the flips (delta_xf ~1e-11).
// Stage 1: conv1 7x7x3->8 VALID + bias + ReLU + 2x2 maxpool -> (64,109,109,8) f64
// Stage 2: conv2 5x5x8->10 VALID + bias + ReLU + 2x2 maxpool -> (64,52,52,10) f64
// Stage 3: fc1 (27040->32) + ReLU, fc2 (32->6) -> theta (64,6) f64
// Stage 4: affine grid + reference-exact bilinear sampler (indices clipped,
//          weights from UNCLIPPED coords -> extrapolation), coords in f64.
// ---------------------------------------------------------------------------

// conv1 + relu + maxpool : in (64,224,224,3) f32 -> out (64,109,109,8) f64
__global__ __launch_bounds__(256) void k_conv1(
    const float* __restrict__ in, const float* __restrict__ w,
    const float* __restrict__ bias, double* __restrict__ out) {
  __shared__ double sw[1176];  // (7,7,3,8) HWIO
  __shared__ double sb[8];
  for (int i = threadIdx.x; i < 1176; i += 256) sw[i] = (double)w[i];
  if (threadIdx.x < 8) sb[threadIdx.x] = (double)bias[threadIdx.x];
  __syncthreads();

  int idx = blockIdx.x * 256 + threadIdx.x;
  if (idx >= 64 * 109 * 109) return;
  int px = idx % 109;
  int t  = idx / 109;
  int py = t % 109;
  int b  = t / 109;

  double acc[2][2][8];
#pragma unroll
  for (int i = 0; i < 2; ++i)
#pragma unroll
    for (int j = 0; j < 2; ++j)
#pragma unroll
      for (int k = 0; k < 8; ++k) acc[i][j][k] = 0.0;

  // input window: rows 2py..2py+7, cols 2px..2px+7, 3 ch (24 floats/row)
  const float* ibase = in + ((size_t)(b * 224 + 2 * py) * 224 + 2 * px) * 3;

  for (int ky = 0; ky < 7; ++ky) {
    const float* r0 = ibase + ky * 672;   // 224*3
    const float* r1 = r0 + 672;
    float a0[24], a1[24];
#pragma unroll
    for (int i = 0; i < 24; ++i) { a0[i] = r0[i]; a1[i] = r1[i]; }
#pragma unroll
    for (int kx = 0; kx < 7; ++kx) {
#pragma unroll
      for (int c = 0; c < 3; ++c) {
        double v00 = (double)a0[kx * 3 + c];
        double v01 = (double)a0[(kx + 1) * 3 + c];
        double v10 = (double)a1[kx * 3 + c];
        double v11 = (double)a1[(kx + 1) * 3 + c];
        const double* wp = &sw[((ky * 7 + kx) * 3 + c) * 8];
#pragma unroll
        for (int oc = 0; oc < 8; ++oc) {
          double wv = wp[oc];
          acc[0][0][oc] += v00 * wv;
          acc[0][1][oc] += v01 * wv;
          acc[1][0][oc] += v10 * wv;
          acc[1][1][oc] += v11 * wv;
        }
      }
    }
  }

  double* op = out + (size_t)idx * 8;
#pragma unroll
  for (int oc = 0; oc < 8; ++oc) {
    double m = fmax(fmax(acc[0][0][oc], acc[0][1][oc]),
                    fmax(acc[1][0][oc], acc[1][1][oc]));
    op[oc] = fmax(m + sb[oc], 0.0);
  }
}

// conv2 + relu + maxpool : in (64,109,109,8) f64 -> out (64,52,52,10) f64
// oc split 5+5 and channel split 4+4 to keep VGPR pressure sane.
__global__ __launch_bounds__(256) void k_conv2(
    const double* __restrict__ in, const float* __restrict__ w,
    const float* __restrict__ bias, double* __restrict__ out) {
  __shared__ double sw[2000];  // (5,5,8,10) HWIO
  __shared__ double sb[10];
  for (int i = threadIdx.x; i < 2000; i += 256) sw[i] = (double)w[i];
  if (threadIdx.x < 10) sb[threadIdx.x] = (double)bias[threadIdx.x];
  __syncthreads();

  int idx = blockIdx.x * 256 + threadIdx.x;
  if (idx >= 64 * 52 * 52) return;
  int px = idx % 52;
  int t  = idx / 52;
  int py = t % 52;
  int b  = t / 52;

  // window: rows 2py..2py+5, cols 2px..2px+5, 8 channels
  const double* ibase = in + ((size_t)(b * 109 + 2 * py) * 109 + 2 * px) * 8;

  for (int oh = 0; oh < 2; ++oh) {  // output-channel halves 0..4 / 5..9
    double acc[2][2][5];
#pragma unroll
    for (int i = 0; i < 2; ++i)
#pragma unroll
      for (int j = 0; j < 2; ++j)
#pragma unroll
        for (int k = 0; k < 5; ++k) acc[i][j][k] = 0.0;

    for (int ky = 0; ky < 5; ++ky) {
      const double* r0 = ibase + (size_t)ky * 872;  // 109*8
      const double* r1 = r0 + 872;
#pragma unroll
      for (int h = 0; h < 2; ++h) {  // input-channel halves 0..3 / 4..7
        double b0[24], b1[24];
#pragma unroll
        for (int j = 0; j < 6; ++j) {
#pragma unroll
          for (int cc = 0; cc < 4; ++cc) {
            b0[j * 4 + cc] = r0[j * 8 + h * 4 + cc];
            b1[j * 4 + cc] = r1[j * 8 + h * 4 + cc];
          }
        }
#pragma unroll
        for (int kx = 0; kx < 5; ++kx) {
#pragma unroll
          for (int cc = 0; cc < 4; ++cc) {
            int c = h * 4 + cc;
            double v00 = b0[kx * 4 + cc];
            double v01 = b0[(kx + 1) * 4 + cc];
            double v10 = b1[kx * 4 + cc];
            double v11 = b1[(kx + 1) * 4 + cc];
            const double* wp = &sw[((ky * 5 + kx) * 8 + c) * 10 + oh * 5];
#pragma unroll
            for (int oc = 0; oc < 5; ++oc) {
              double wv = wp[oc];
              acc[0][0][oc] += v00 * wv;
              acc[0][1][oc] += v01 * wv;
              acc[1][0][oc] += v10 * wv;
              acc[1][1][oc] += v11 * wv;
            }
          }
        }
      }
    }

    double* op = out + (size_t)idx * 10 + oh * 5;
#pragma unroll
    for (int oc = 0; oc < 5; ++oc) {
      double m = fmax(fmax(acc[0][0][oc], acc[0][1][oc]),
                      fmax(acc[1][0][oc], acc[1][1][oc]));
      op[oc] = fmax(m + sb[oh * 5 + oc], 0.0);
    }
  }
}

// fc1 (27040->32) + ReLU, then fc2 (32->6). One block per batch, fp64.
__global__ __launch_bounds__(256) void k_fc(
    const double* __restrict__ xs, const float* __restrict__ w1,
    const float* __restrict__ b1, const float* __restrict__ w2,
    const float* __restrict__ b2, double* __restrict__ theta) {
  int b = blockIdx.x;
  int oc = threadIdx.x & 31;
  int chunk = threadIdx.x >> 5;  // 8 chunks of 3380
  const double* xrow = xs + (size_t)b * 27040;

  double s = 0.0;
  int i0 = chunk * 3380;
  for (int i = 0; i < 3380; ++i) {
    s += xrow[i0 + i] * (double)w1[(size_t)(i0 + i) * 32 + oc];
  }

  __shared__ double part[8][32];
  part[chunk][oc] = s;
  __syncthreads();

  __shared__ double h1[32];
  if (threadIdx.x < 32) {
    double v = (double)b1[threadIdx.x];
#pragma unroll
    for (int k = 0; k < 8; ++k) v += part[k][threadIdx.x];
    h1[threadIdx.x] = v > 0.0 ? v : 0.0;
  }
  __syncthreads();

  if (threadIdx.x < 6) {
    double v = (double)b2[threadIdx.x];
#pragma unroll
    for (int k = 0; k < 32; ++k) v += h1[k] * (double)w2[k * 6 + threadIdx.x];
    theta[b * 6 + threadIdx.x] = v;
  }
}

// affine grid + bilinear sampler, reference-exact (incl. extrapolation quirk).
__global__ __launch_bounds__(256) void k_sample(
    const float* __restrict__ img, const double* __restrict__ theta,
    float* __restrict__ out) {
  int idx = blockIdx.x * 256 + threadIdx.x;
  if (idx >= 64 * 224 * 224) return;
  int x = idx % 224;
  int t = idx / 224;
  int y = t % 224;
  int b = t / 224;

  const double* th = theta + b * 6;
  double t0 = th[0], t1 = th[1], t2 = th[2];
  double t3 = th[3], t4 = th[4], t5 = th[5];

  double xn = -1.0 + x * (2.0 / 223.0);
  double yn = -1.0 + y * (2.0 / 223.0);
  double xf = 0.5 * (t0 * xn + t1 * yn + t2 + 1.0) * 223.0;
  double yf = 0.5 * (t3 * xn + t4 * yn + t5 + 1.0) * 223.0;

  int x0 = (int)floor(xf);
  int y0 = (int)floor(yf);
  x0 = min(max(x0, 0), 223);
  y0 = min(max(y0, 0), 223);
  int x1 = min(x0 + 1, 223);
  int y1 = min(y0 + 1, 223);

  double x0f = (double)x0, x1f = (double)x1;
  double y0f = (double)y0, y1f = (double)y1;
  // weights from UNCLIPPED xf/yf — reference semantics (extrapolates for <0)
  double wa = (x1f - xf) * (y1f - yf);
  double wb = (x1f - xf) * (yf - y0f);
  double wc = (xf - x0f) * (y1f - yf);
  double wd = (xf - x0f) * (yf - y0f);

  const float* p = img + (size_t)b * 224 * 224 * 3;
  const float* Ia = p + ((size_t)y0 * 224 + x0) * 3;
  const float* Ib = p + ((size_t)y1 * 224 + x0) * 3;
  const float* Ic = p + ((size_t)y0 * 224 + x1) * 3;
  const float* Id = p + ((size_t)y1 * 224 + x1) * 3;

  float* op = out + (size_t)idx * 3;
#pragma unroll
  for (int c = 0; c < 3; ++c) {
    op[c] = (float)(wa * (double)Ia[c] + wb * (double)Ib[c] +
                    wc * (double)Ic[c] + wd * (double)Id[c]);
  }
}

extern "C" void kernel_launch(void* const* d_in, const int* in_sizes, int n_in,
                              void* d_out, int out_size, void* d_ws, size_t ws_size,
                              hipStream_t stream) {
  const float* inputs  = (const float*)d_in[0];  // (64,224,224,3)
  const float* conv1_w = (const float*)d_in[1];  // (7,7,3,8)
  const float* conv1_b = (const float*)d_in[2];  // (8)
  const float* conv2_w = (const float*)d_in[3];  // (5,5,8,10)
  const float* conv2_b = (const float*)d_in[4];  // (10)
  const float* fc1_w   = (const float*)d_in[5];  // (27040,32)
  const float* fc1_b   = (const float*)d_in[6];  // (32)
  const float* fc2_w   = (const float*)d_in[7];  // (32,6)
  const float* fc2_b   = (const float*)d_in[8];  // (6)
  float* outp = (float*)d_out;                   // (64,224,224,3)

  // ws layout (all 8B aligned): theta, pool1 f64, pool2 f64  (~62.5 MB)
  double* theta = (double*)d_ws;                    // 64*6
  double* pool1 = (double*)((char*)d_ws + 4096);    // 64*109*109*8 = 6,081,152
  double* pool2 = pool1 + 6081152;                  // 64*52*52*10  = 1,730,560

  // Stage 1
  {
    int total = 64 * 109 * 109;
    int blocks = (total + 255) / 256;
    k_conv1<<<blocks, 256, 0, stream>>>(inputs, conv1_w, conv1_b, pool1);
  }
  // Stage 2
  {
    int total = 64 * 52 * 52;
    int blocks = (total + 255) / 256;
    k_conv2<<<blocks, 256, 0, stream>>>(pool1, conv2_w, conv2_b, pool2);
  }
  // Stage 3
  k_fc<<<64, 256, 0, stream>>>(pool2, fc1_w, fc1_b, fc2_w, fc2_b, theta);
  // Stage 4
  {
    int total = 64 * 224 * 224;
    int blocks = (total + 255) / 256;
    k_sample<<<blocks, 256, 0, stream>>>(inputs, theta, outp);
  }
}